// Round 2
// baseline (136.201 us; speedup 1.0000x reference)
//
#include <hip/hip_runtime.h>
#include <math.h>

constexpr int BS = 16;
constexpr int G  = 512;
constexpr int S  = 20;
constexpr int Q  = 256;
constexpr int P  = G * S;            // 10240
constexpr int PCHUNK = 256;
constexpr int NCHUNK = P / PCHUNK;   // 40
constexpr float THRESHOLD = 0.01f;
constexpr float BIG  = 1e10f;
constexpr float FARV = 1e15f;        // sentinel coord for masked-out pred points
constexpr float FINF = 3.4e38f;

// Workspace layout (float/uint words):
// [0..15]    cd1 accum per batch (atomicAdd, zero-init by bce_init)
// [16..47]   bce partial per bce block (written, no init needed)
// [48..79]   cell-count partial per bce block (float)
// [80..4175] qmin[BS*Q] as uint bits (init BIG by bce_init)
constexpr int WS_CD1  = 0;
constexpr int WS_BCEP = 16;
constexpr int WS_CNTP = 48;
constexpr int WS_QMIN = 80;

// grid 32 x 256: BCE partials + mask-cell-count partials + ws init.
__global__ void bce_init_kernel(const float* __restrict__ probs,
                                const float* __restrict__ target,
                                float* __restrict__ ws) {
    int tid = threadIdx.x;
    int gid = blockIdx.x * 256 + tid;           // 0..8191 == BS*G

    // init sections used by chamfer (runs strictly after on same stream)
    if (gid < BS * Q) ((unsigned*)ws)[WS_QMIN + gid] = __float_as_uint(BIG);
    if (gid < 16)     ws[WS_CD1 + gid] = 0.0f;

    float p = probs[gid];
    float t = target[gid];
    float logp   = fmaxf(logf(p), -100.0f);
    float log1mp = fmaxf(log1pf(-p), -100.0f);
    float term = -(t * logp + (1.0f - t) * log1mp);
    float c = (p > THRESHOLD) ? 1.0f : 0.0f;

    for (int off = 32; off; off >>= 1) {
        term += __shfl_down(term, off);
        c    += __shfl_down(c, off);
    }
    __shared__ float st[4], sc[4];
    int w = tid >> 6;
    if ((tid & 63) == 0) { st[w] = term; sc[w] = c; }
    __syncthreads();
    if (tid == 0) {
        ws[WS_BCEP + blockIdx.x] = st[0] + st[1] + st[2] + st[3];
        ws[WS_CNTP + blockIdx.x] = sc[0] + sc[1] + sc[2] + sc[3];
    }
}

// grid = BS*NCHUNK blocks x 512 threads. Block: batch b, 256-pred-point chunk.
// Thread pair (2*i, 2*i+1) shares point i; each scans half of the opposing set.
__global__ __launch_bounds__(512) void chamfer_kernel(
        const float* __restrict__ diff_pred,   // [BS,P,3]
        const float* __restrict__ probs,       // [BS,G]
        const float* __restrict__ diff_gt,     // [BS,Q,3]
        float* __restrict__ ws) {
    int b     = blockIdx.x / NCHUNK;
    int chunk = blockIdx.x % NCHUNK;
    int tid   = threadIdx.x;

    __shared__ float4 sg[256];   // gt points (w unused)
    __shared__ float4 sp[256];   // pred points; masked-out -> FARV coords; w = mask

    if (tid < 256) {
        const float* gp = diff_gt + ((size_t)b * Q + tid) * 3;
        sg[tid] = make_float4(gp[0], gp[1], gp[2], 0.0f);
    } else {
        int j = tid - 256;
        int p = chunk * PCHUNK + j;
        const float* pp = diff_pred + ((size_t)b * P + p) * 3;
        bool m = probs[b * G + p / S] > THRESHOLD;
        float x = pp[0], y = pp[1], z = pp[2];
        sp[j] = make_float4(m ? x : FARV, m ? y : FARV, m ? z : FARV, m ? 1.0f : 0.0f);
    }
    __syncthreads();

    int idx  = tid >> 1;     // owned point index (0..255)
    int half = tid & 1;      // which half of the opposing set to scan

    // Phase 1 (cd1): pair owns pred point idx; min d2 over its half of gt.
    {
        float4 own = sp[idx];
        float mn0 = FINF, mn1 = FINF, mn2 = FINF, mn3 = FINF;
        const float4* g = sg + half * 128;
        #pragma unroll 2
        for (int q = 0; q < 128; q += 4) {
            float4 g0 = g[q], g1 = g[q + 1], g2 = g[q + 2], g3 = g[q + 3];
            float dx, dy, dz;
            dx = own.x - g0.x; dy = own.y - g0.y; dz = own.z - g0.z;
            mn0 = fminf(mn0, dx * dx + dy * dy + dz * dz);
            dx = own.x - g1.x; dy = own.y - g1.y; dz = own.z - g1.z;
            mn1 = fminf(mn1, dx * dx + dy * dy + dz * dz);
            dx = own.x - g2.x; dy = own.y - g2.y; dz = own.z - g2.z;
            mn2 = fminf(mn2, dx * dx + dy * dy + dz * dz);
            dx = own.x - g3.x; dy = own.y - g3.y; dz = own.z - g3.z;
            mn3 = fminf(mn3, dx * dx + dy * dy + dz * dz);
        }
        float mn = fminf(fminf(mn0, mn1), fminf(mn2, mn3));
        mn = fminf(mn, __shfl_xor(mn, 1));                 // merge the two halves
        float contrib = (half == 0 && own.w != 0.0f) ? sqrtf(mn) : 0.0f;
        for (int off = 32; off; off >>= 1) contrib += __shfl_down(contrib, off);
        if ((tid & 63) == 0) atomicAdd(&ws[WS_CD1 + b], contrib);
    }

    // Phase 2 (cd2): pair owns gt point idx; min d2 over its half of masked pred.
    // Masked-out pred points sit at FARV so their d2 ~ 1e30 >> any real distance.
    {
        float4 own = sg[idx];
        float mn0 = FINF, mn1 = FINF, mn2 = FINF, mn3 = FINF;
        const float4* g = sp + half * 128;
        #pragma unroll 2
        for (int j = 0; j < 128; j += 4) {
            float4 g0 = g[j], g1 = g[j + 1], g2 = g[j + 2], g3 = g[j + 3];
            float dx, dy, dz;
            dx = own.x - g0.x; dy = own.y - g0.y; dz = own.z - g0.z;
            mn0 = fminf(mn0, dx * dx + dy * dy + dz * dz);
            dx = own.x - g1.x; dy = own.y - g1.y; dz = own.z - g1.z;
            mn1 = fminf(mn1, dx * dx + dy * dy + dz * dz);
            dx = own.x - g2.x; dy = own.y - g2.y; dz = own.z - g2.z;
            mn2 = fminf(mn2, dx * dx + dy * dy + dz * dz);
            dx = own.x - g3.x; dy = own.y - g3.y; dz = own.z - g3.z;
            mn3 = fminf(mn3, dx * dx + dy * dy + dz * dz);
        }
        float mn = fminf(fminf(mn0, mn1), fminf(mn2, mn3));
        mn = fminf(mn, __shfl_xor(mn, 1));
        if (half == 0) {
            float v = sqrtf(mn);   // ~1e15 if no masked point in chunk; > BIG, so harmless
            atomicMin(&((unsigned*)ws)[WS_QMIN + b * Q + idx], __float_as_uint(v));
        }
    }
}

// 1 block x 1024 threads: wave w reduces batch w; thread 0 combines.
__global__ void finalize_kernel(const float* __restrict__ ws, float* __restrict__ out) {
    int tid = threadIdx.x;
    int w = tid >> 6, lane = tid & 63;
    __shared__ float scd[16];

    const unsigned* qm = (const unsigned*)ws + WS_QMIN + w * Q;
    float s = __uint_as_float(qm[lane])       + __uint_as_float(qm[lane + 64]) +
              __uint_as_float(qm[lane + 128]) + __uint_as_float(qm[lane + 192]);
    for (int off = 32; off; off >>= 1) s += __shfl_down(s, off);
    if (lane == 0) {
        float cd2   = s / (float)Q;
        float cells = ws[WS_CNTP + 2 * w] + ws[WS_CNTP + 2 * w + 1];
        float cnt   = cells * (float)S;
        float cd1   = ws[WS_CD1 + w] / fmaxf(cnt, 1.0f);
        scd[w] = (cnt > 0.0f) ? fmaxf(cd1, cd2) : 0.0f;
    }
    __syncthreads();
    if (tid == 0) {
        float bce = 0.0f;
        #pragma unroll
        for (int i = 0; i < 32; ++i) bce += ws[WS_BCEP + i];
        float cds = 0.0f;
        #pragma unroll
        for (int i = 0; i < 16; ++i) cds += scd[i];
        out[0] = bce / (float)(BS * G) + cds / (float)BS;
    }
}

extern "C" void kernel_launch(void* const* d_in, const int* in_sizes, int n_in,
                              void* d_out, int out_size, void* d_ws, size_t ws_size,
                              hipStream_t stream) {
    const float* diff_pred   = (const float*)d_in[0];
    const float* probs_pred  = (const float*)d_in[1];
    const float* diff_gt     = (const float*)d_in[2];
    const float* prob_target = (const float*)d_in[3];
    float* out = (float*)d_out;
    float* ws  = (float*)d_ws;

    bce_init_kernel<<<BS * G / 256, 256, 0, stream>>>(probs_pred, prob_target, ws);
    chamfer_kernel<<<BS * NCHUNK, 512, 0, stream>>>(diff_pred, probs_pred, diff_gt, ws);
    finalize_kernel<<<1, 1024, 0, stream>>>(ws, out);
}

// Round 4
// 108.123 us; speedup vs baseline: 1.2597x; 1.2597x over previous
//
#include <hip/hip_runtime.h>
#include <math.h>

constexpr int BS = 16;
constexpr int G  = 512;
constexpr int S  = 20;
constexpr int Q  = 256;
constexpr int P  = G * S;            // 10240
constexpr int NCHUNK = P / 256;      // 40
constexpr int NBLK   = BS * NCHUNK;  // 640 blocks per phase
constexpr float THRESHOLD = 0.01f;
constexpr float BIG  = 1e10f;
constexpr float FARV = 1e15f;        // sentinel coords for masked-out pred points
constexpr float FINF = 3.4e38f;

// ---- big-ws layout (floats) ----
constexpr int WQ   = 0;                       // qpart[BS][NCHUNK][Q] = 163840
constexpr int WC1  = WQ + BS * NCHUNK * Q;    // cd1part[640]
constexpr int WB   = WC1 + NBLK;              // bcep[32]
constexpr int WCN  = WB + 32;                 // cntp[32]
constexpr int WTOT = WCN + 32;                // 164544 floats (~658 KB)
// ---- small-ws fallback layout (floats) ----
constexpr int SQM  = 0;                       // qmin[BS*Q] uint bits
constexpr int SC1  = SQM + BS * Q;            // cd1[16]
constexpr int SB   = SC1 + 16;                // bcep[32]
constexpr int SCN  = SB + 32;                 // cntp[32]

__global__ void init_small_kernel(float* ws) {
    int i = blockIdx.x * 256 + threadIdx.x;
    if (i < 16) ws[SC1 + i] = 0.0f;
    if (i < BS * Q) ((unsigned*)ws)[SQM + i] = __float_as_uint(BIG);
}

// grid = 2*NBLK x 256. Blocks [0,640): phase 1 (cd1). Blocks [640,1280): phase 2 (cd2).
// Each block: one batch b, one 256-point pred chunk. Own point in registers;
// opposing set staged SoA in LDS, read as uniform float4 broadcasts (conflict-free).
template<bool BIGWS>
__global__ __launch_bounds__(256) void chamfer_kernel(
        const float* __restrict__ pred,     // [BS,P,3]
        const float* __restrict__ probs,    // [BS,G]
        const float* __restrict__ gt,       // [BS,Q,3]
        const float* __restrict__ target,   // [BS,G]
        float* __restrict__ ws) {
    int bid   = blockIdx.x;
    int phase = (bid >= NBLK) ? 1 : 0;
    int id    = phase ? bid - NBLK : bid;
    int b     = id / NCHUNK;
    int chunk = id % NCHUNK;
    int t     = threadIdx.x;

    __shared__ float4 sx4[64], sy4[64], sz4[64];
    float* sx = (float*)sx4; float* sy = (float*)sy4; float* sz = (float*)sz4;
    __shared__ float part[4], bpart[4], cpart[4];

    float ox, oy, oz;
    bool  om = true;
    if (!phase) {
        // stage gt; own = pred point
        const float* gp = gt + ((size_t)b * Q + t) * 3;
        sx[t] = gp[0]; sy[t] = gp[1]; sz[t] = gp[2];
        int p = chunk * 256 + t;
        const float* pp = pred + ((size_t)b * P + p) * 3;
        ox = pp[0]; oy = pp[1]; oz = pp[2];
        om = probs[b * G + p / S] > THRESHOLD;
    } else {
        // stage mask-folded pred; own = gt point
        int p = chunk * 256 + t;
        const float* pp = pred + ((size_t)b * P + p) * 3;
        bool m = probs[b * G + p / S] > THRESHOLD;
        sx[t] = m ? pp[0] : FARV;
        sy[t] = m ? pp[1] : FARV;
        sz[t] = m ? pp[2] : FARV;
        const float* gp = gt + ((size_t)b * Q + t) * 3;
        ox = gp[0]; oy = gp[1]; oz = gp[2];
    }

    // BCE partials on the first 32 blocks (block-uniform branch)
    if (bid < 32) {
        int cell = bid * 256 + t;
        float pv = probs[cell];
        float tv = target[cell];
        float term = -(tv * fmaxf(logf(pv), -100.0f) +
                       (1.0f - tv) * fmaxf(log1pf(-pv), -100.0f));
        float c = (pv > THRESHOLD) ? 1.0f : 0.0f;
        for (int off = 32; off; off >>= 1) {
            term += __shfl_down(term, off);
            c    += __shfl_down(c, off);
        }
        if ((t & 63) == 0) { bpart[t >> 6] = term; cpart[t >> 6] = c; }
    }
    __syncthreads();

    if (bid < 32 && t == 0) {
        ws[(BIGWS ? WB  : SB)  + bid] = bpart[0] + bpart[1] + bpart[2] + bpart[3];
        ws[(BIGWS ? WCN : SCN) + bid] = cpart[0] + cpart[1] + cpart[2] + cpart[3];
    }

    // min squared distance: own point vs 256 staged points, 4 at a time
    float mn0 = FINF, mn1 = FINF, mn2 = FINF, mn3 = FINF;
    #pragma unroll 4
    for (int g = 0; g < 64; ++g) {
        float4 X = sx4[g], Y = sy4[g], Z = sz4[g];
        float dx, dy, dz, d;
        dx = ox - X.x; dy = oy - Y.x; dz = oz - Z.x;
        d = dx * dx + dy * dy + dz * dz; mn0 = fminf(mn0, d);
        dx = ox - X.y; dy = oy - Y.y; dz = oz - Z.y;
        d = dx * dx + dy * dy + dz * dz; mn1 = fminf(mn1, d);
        dx = ox - X.z; dy = oy - Y.z; dz = oz - Z.z;
        d = dx * dx + dy * dy + dz * dz; mn2 = fminf(mn2, d);
        dx = ox - X.w; dy = oy - Y.w; dz = oz - Z.w;
        d = dx * dx + dy * dy + dz * dz; mn3 = fminf(mn3, d);
    }
    float mn = fminf(fminf(mn0, mn1), fminf(mn2, mn3));

    if (!phase) {
        float contrib = om ? sqrtf(mn) : 0.0f;
        for (int off = 32; off; off >>= 1) contrib += __shfl_down(contrib, off);
        if ((t & 63) == 0) part[t >> 6] = contrib;
        __syncthreads();
        if (t == 0) {
            float s = part[0] + part[1] + part[2] + part[3];
            if (BIGWS) ws[WC1 + id] = s;
            else       atomicAdd(&ws[SC1 + b], s);
        }
    } else {
        float v = sqrtf(mn);   // ~1.7e15 if chunk fully unmasked; min-reduced away later
        if (BIGWS) ws[WQ + id * Q + t] = v;
        else       atomicMin((unsigned*)ws + SQM + b * Q + t, __float_as_uint(v));
    }
}

// 1 block x 1024 threads.
__global__ __launch_bounds__(1024) void finalize_big_kernel(
        const float* __restrict__ ws, float* __restrict__ out) {
    int tid = threadIdx.x;
    __shared__ float sums[16][4];
    __shared__ float scd1[16], scnt[16], sbce[1];
    if (tid < 16) { scd1[tid] = 0.0f; scnt[tid] = 0.0f; }
    if (tid == 0) sbce[0] = 0.0f;
    __syncthreads();

    // qpart: min over 40 chunks per (b,q), then per-batch sum
    for (int k = 0; k < 4; ++k) {
        int id = k * 1024 + tid;         // 0..4095 = (b,q)
        int b = id >> 8, q = id & 255;
        const float* qp = ws + WQ + (size_t)b * NCHUNK * Q + q;
        float mn = FINF;
        #pragma unroll 8
        for (int c = 0; c < NCHUNK; ++c) mn = fminf(mn, qp[c * Q]);
        float s = mn;
        for (int off = 32; off; off >>= 1) s += __shfl_down(s, off);
        int w = tid >> 6;                // b is wave-uniform: b = 4k + (w>>2)
        if ((tid & 63) == 0) sums[b][w & 3] = s;
    }
    if (tid < NBLK) atomicAdd(&scd1[tid / NCHUNK], ws[WC1 + tid]);
    if (tid < 32) {
        atomicAdd(&sbce[0], ws[WB + tid]);
        atomicAdd(&scnt[tid >> 1], ws[WCN + tid]);
    }
    __syncthreads();

    if (tid == 0) {
        float acc = 0.0f;
        #pragma unroll
        for (int b = 0; b < 16; ++b) {
            float cd2 = (sums[b][0] + sums[b][1] + sums[b][2] + sums[b][3]) / (float)Q;
            float cnt = scnt[b] * (float)S;
            float cd1 = scd1[b] / fmaxf(cnt, 1.0f);
            acc += (cnt > 0.0f) ? fmaxf(cd1, cd2) : 0.0f;
        }
        out[0] = sbce[0] / (float)(BS * G) + acc / (float)BS;
    }
}

// fallback finalize: qmin already merged via atomicMin
__global__ __launch_bounds__(1024) void finalize_small_kernel(
        const float* __restrict__ ws, float* __restrict__ out) {
    int tid = threadIdx.x;
    int w = tid >> 6, lane = tid & 63;
    __shared__ float scd[16], scnt[16], sbce[1];
    if (tid < 16) scnt[tid] = 0.0f;
    if (tid == 0) sbce[0] = 0.0f;
    __syncthreads();
    if (tid < 32) {
        atomicAdd(&sbce[0], ws[SB + tid]);
        atomicAdd(&scnt[tid >> 1], ws[SCN + tid]);
    }
    const unsigned* qm = (const unsigned*)ws + SQM + w * Q;
    float s = __uint_as_float(qm[lane])       + __uint_as_float(qm[lane + 64]) +
              __uint_as_float(qm[lane + 128]) + __uint_as_float(qm[lane + 192]);
    for (int off = 32; off; off >>= 1) s += __shfl_down(s, off);
    if (lane == 0) scd[w] = s;
    __syncthreads();
    if (tid == 0) {
        float acc = 0.0f;
        #pragma unroll
        for (int b = 0; b < 16; ++b) {
            float cnt = scnt[b] * (float)S;
            float cd1 = ws[SC1 + b] / fmaxf(cnt, 1.0f);
            float cd2 = scd[b] / (float)Q;
            acc += (cnt > 0.0f) ? fmaxf(cd1, cd2) : 0.0f;
        }
        out[0] = sbce[0] / (float)(BS * G) + acc / (float)BS;
    }
}

extern "C" void kernel_launch(void* const* d_in, const int* in_sizes, int n_in,
                              void* d_out, int out_size, void* d_ws, size_t ws_size,
                              hipStream_t stream) {
    const float* diff_pred   = (const float*)d_in[0];
    const float* probs_pred  = (const float*)d_in[1];
    const float* diff_gt     = (const float*)d_in[2];
    const float* prob_target = (const float*)d_in[3];
    float* out = (float*)d_out;
    float* ws  = (float*)d_ws;

    if (ws_size >= (size_t)WTOT * sizeof(float)) {
        chamfer_kernel<true><<<2 * NBLK, 256, 0, stream>>>(
            diff_pred, probs_pred, diff_gt, prob_target, ws);
        finalize_big_kernel<<<1, 1024, 0, stream>>>(ws, out);
    } else {
        init_small_kernel<<<16, 256, 0, stream>>>(ws);
        chamfer_kernel<false><<<2 * NBLK, 256, 0, stream>>>(
            diff_pred, probs_pred, diff_gt, prob_target, ws);
        finalize_small_kernel<<<1, 1024, 0, stream>>>(ws, out);
    }
}